// Round 2
// baseline (523.573 us; speedup 1.0000x reference)
//
#include <hip/hip_runtime.h>

#define ND 64
#define NPAIR 6

typedef short bf16x8 __attribute__((ext_vector_type(8)));
typedef float floatx4 __attribute__((ext_vector_type(4)));

static constexpr int SPB  = 8;              // samples per block
static constexpr int ROWS = SPB * NPAIR;    // 48 rows = 3 waves x 16 rows (one MFMA M-tile each)
static constexpr int DSTR = 72;             // halfwords per A_d row (64 + 8 pad; 144B keeps b128 reads 16B-aligned)

__device__ __forceinline__ unsigned short f2bf(float f) {
    unsigned u = __builtin_bit_cast(unsigned, f);
    u += 0x7FFFu + ((u >> 16) & 1u);        // round-to-nearest-even (no NaN inputs)
    return (unsigned short)(u >> 16);
}
__device__ __forceinline__ unsigned f2bf2(float lo, float hi) {
    return (unsigned)f2bf(lo) | ((unsigned)f2bf(hi) << 16);
}

// Repack W1..3 [o][i][k] fp32 -> bf16 B-operand layout P[L][n=o][j], j<128: (i=j>>1,k=j&1), j>=128: (i=j-128,k=2)
__global__ void repack_w(const float* __restrict__ W1, const float* __restrict__ W2,
                         const float* __restrict__ W3, unsigned short* __restrict__ P) {
    int idx = blockIdx.x * 256 + threadIdx.x;
    if (idx >= 3 * 64 * 192) return;
    int j = idx % 192;
    int n = (idx / 192) % 64;
    int L = idx / (192 * 64);
    const float* W = (L == 0) ? W1 : (L == 1) ? W2 : W3;
    float v = (j < 128) ? W[n * 192 + (j >> 1) * 3 + (j & 1)]
                        : W[n * 192 + (j - 128) * 3 + 2];
    P[idx] = f2bf(v);
}

// 3 waves/block; wave w owns rows 16w..16w+15 (wave-private through all 3 layers).
// Layer loop has ZERO barriers: x-part A-frags live in registers, d-part round-trips
// through wave-private LDS rows. Channel-permuted B (ntile nt covers ch=4*l15+nt) so
// each lane's 4 outputs per row are consecutive channels -> single b64 d-part write.
__global__ __launch_bounds__(192, 4) void dijet_main(
    const float* __restrict__ x, const float* __restrict__ d,
    const float* __restrict__ b1, const float* __restrict__ b2,
    const float* __restrict__ b3, const unsigned short* __restrict__ Wp,
    float* __restrict__ out)
{
    __shared__ __align__(16) unsigned short Adp[ROWS * DSTR];   // 6912 B: d-part only
    __shared__ __align__(16) float Ct[SPB * ND * NPAIR];        // 12288 B: fp32 out transpose

    const int t    = threadIdx.x;
    const int b0   = blockIdx.x * SPB;
    const int wv   = t >> 6;
    const int lane = t & 63;
    const int l15  = lane & 15;
    const int quad = lane >> 4;

    // ---- d: coalesced float2 loads; keep residual in regs; scatter to Adp (one-time)
    float2 dres[SPB];
    {
        const float2* d2 = (const float2*)(d + (size_t)b0 * (ND * NPAIR));
        #pragma unroll
        for (int m = 0; m < SPB; ++m) dres[m] = d2[m * 192 + t];
        const int di  = t / 3;                 // channel
        const int dsl = 2 * (t - 3 * (t / 3)); // even slot
        #pragma unroll
        for (int m = 0; m < SPB; ++m) {
            Adp[(m * 6 + dsl)     * DSTR + di] = f2bf(dres[m].x);
            Adp[(m * 6 + dsl + 1) * DSTR + di] = f2bf(dres[m].y);
        }
    }

    // ---- x: per-lane direct global->register fragments (static across all 3 layers)
    const int row = 16 * wv + l15;             // this lane's A-row (as A-operand m index)
    const int bs  = row / 6;
    const int ss  = row - 6 * bs;
    bf16x8 Ax[4];
    {
        const float* xb = x + (size_t)(b0 + bs) * (ND * 12) + 2 * ss;
        #pragma unroll
        for (int kk = 0; kk < 4; ++kk) {
            union { bf16x8 h; unsigned u[4]; } tmp;
            #pragma unroll
            for (int w = 0; w < 4; ++w) {
                const float2 v = *(const float2*)(xb + (kk * 16 + quad * 4 + w) * 12);
                tmp.u[w] = f2bf2(v.x, v.y);
            }
            Ax[kk] = tmp.h;
        }
    }
    __syncthreads();                           // Adp staged by all threads

    const unsigned short* Arow = Adp + (16 * wv + l15) * DSTR + quad * 8;

    #pragma unroll
    for (int L = 0; L < 3; ++L) {
        const float* bL = (L == 0) ? b1 : (L == 1) ? b2 : b3;
        const unsigned short* WL = Wp + L * (64 * 192) + quad * 8;

        // d-part A-fragments (wave-private rows; in-order LDS ensures prev layer's writes seen)
        const bf16x8 Ad0 = *(const bf16x8*)(Arow);        // k = 128..159
        const bf16x8 Ad1 = *(const bf16x8*)(Arow + 32);   // k = 160..191

        float bias[4];
        floatx4 acc[4];
        #pragma unroll
        for (int nt = 0; nt < 4; ++nt) {
            const int ch = 4 * l15 + nt;                  // output channel at this lane/ntile
            const unsigned short* wr = WL + ch * 192;
            bias[nt] = bL[ch];
            floatx4 a = {0.f, 0.f, 0.f, 0.f};
            a = __builtin_amdgcn_mfma_f32_16x16x32_bf16(Ax[0], *(const bf16x8*)(wr),       a, 0, 0, 0);
            a = __builtin_amdgcn_mfma_f32_16x16x32_bf16(Ax[1], *(const bf16x8*)(wr + 32),  a, 0, 0, 0);
            a = __builtin_amdgcn_mfma_f32_16x16x32_bf16(Ax[2], *(const bf16x8*)(wr + 64),  a, 0, 0, 0);
            a = __builtin_amdgcn_mfma_f32_16x16x32_bf16(Ax[3], *(const bf16x8*)(wr + 96),  a, 0, 0, 0);
            a = __builtin_amdgcn_mfma_f32_16x16x32_bf16(Ad0,   *(const bf16x8*)(wr + 128), a, 0, 0, 0);
            a = __builtin_amdgcn_mfma_f32_16x16x32_bf16(Ad1,   *(const bf16x8*)(wr + 160), a, 0, 0, 0);
            acc[nt] = a;
        }

        if (L < 2) {
            // new d-part, relu'd; lane holds rows quad*4+r, consecutive channels 4*l15..+3 -> b64
            #pragma unroll
            for (int r = 0; r < 4; ++r) {
                float v0 = acc[0][r] + bias[0]; v0 = v0 > 0.f ? v0 : 0.f;
                float v1 = acc[1][r] + bias[1]; v1 = v1 > 0.f ? v1 : 0.f;
                float v2 = acc[2][r] + bias[2]; v2 = v2 > 0.f ? v2 : 0.f;
                float v3 = acc[3][r] + bias[3]; v3 = v3 > 0.f ? v3 : 0.f;
                uint2 pk;
                pk.x = f2bf2(v0, v1);
                pk.y = f2bf2(v2, v3);
                *(uint2*)(Adp + (16 * wv + quad * 4 + r) * DSTR + 4 * l15) = pk;
            }
            // no barrier: rows are wave-private; lgkmcnt ordering suffices
        } else {
            // transpose conv3 output (+bias, NO relu yet) into [b][ch*6+s] fp32
            #pragma unroll
            for (int nt = 0; nt < 4; ++nt) {
                #pragma unroll
                for (int r = 0; r < 4; ++r) {
                    const int rw = 16 * wv + quad * 4 + r;
                    const int bl = rw / 6;
                    const int s  = rw - 6 * bl;
                    Ct[bl * (ND * NPAIR) + (4 * l15 + nt) * NPAIR + s] = acc[nt][r] + bias[nt];
                }
            }
            __syncthreads();
            // coalesced store fused with register-resident residual + final relu
            float2* out2 = (float2*)(out + (size_t)b0 * (ND * NPAIR));
            const float2* Ct2 = (const float2*)Ct;
            #pragma unroll
            for (int m = 0; m < SPB; ++m) {
                float2 c = Ct2[m * 192 + t];
                float2 rv;
                rv.x = c.x + dres[m].x; rv.x = rv.x > 0.f ? rv.x : 0.f;
                rv.y = c.y + dres[m].y; rv.y = rv.y > 0.f ? rv.y : 0.f;
                out2[m * 192 + t] = rv;
            }
        }
    }
}

extern "C" void kernel_launch(void* const* d_in, const int* in_sizes, int n_in,
                              void* d_out, int out_size, void* d_ws, size_t ws_size,
                              hipStream_t stream)
{
    const float* x  = (const float*)d_in[0];
    const float* dd = (const float*)d_in[1];
    const float* W1 = (const float*)d_in[2];
    const float* b1 = (const float*)d_in[3];
    const float* W2 = (const float*)d_in[4];
    const float* b2 = (const float*)d_in[5];
    const float* W3 = (const float*)d_in[6];
    const float* b3 = (const float*)d_in[7];
    float* out = (float*)d_out;
    unsigned short* Wp = (unsigned short*)d_ws;   // 3*64*192*2 = 73728 B

    int n = in_sizes[0] / (ND * 12);              // 65536

    repack_w<<<144, 256, 0, stream>>>(W1, W2, W3, Wp);
    dijet_main<<<n / SPB, 192, 0, stream>>>(x, dd, b1, b2, b3, Wp, out);
}

// Round 3
// 393.818 us; speedup vs baseline: 1.3295x; 1.3295x over previous
//
#include <hip/hip_runtime.h>

#define ND 64
#define NPAIR 6

typedef short bf16x8 __attribute__((ext_vector_type(8)));
typedef float floatx4 __attribute__((ext_vector_type(4)));

static constexpr int SPB  = 8;             // samples per block
static constexpr int ROWS = SPB * NPAIR;   // 48 M-rows per block

__device__ __forceinline__ unsigned short f2bf(float f) {
    unsigned u = __builtin_bit_cast(unsigned, f);
    u += 0x7FFFu + ((u >> 16) & 1u);       // round-to-nearest-even (no NaN inputs)
    return (unsigned short)(u >> 16);
}
__device__ __forceinline__ unsigned f2bf2(float lo, float hi) {
    return (unsigned)f2bf(lo) | ((unsigned)f2bf(hi) << 16);
}

// XOR chunk swizzle (chunk = 8 halfwords = 16B). Makes stride-128/64-halfword rows
// conflict-free on ds_read_b128: banks become 4*((c^row)&7), 2 lanes/bank (free).
__device__ __forceinline__ int swzAx(int row, int c) { return (c & 8) | ((c ^ row) & 7); }  // c in 0..15
__device__ __forceinline__ int swzD (int row, int c) { return (c ^ row) & 7; }              // c in 0..7

// Repack W1..3 [o][i][k] fp32 -> bf16 B-operand layout P[L][n=o][j], j<128: (i=j>>1,k=j&1), j>=128: (i=j-128,k=2)
__global__ void repack_w(const float* __restrict__ W1, const float* __restrict__ W2,
                         const float* __restrict__ W3, unsigned short* __restrict__ P) {
    int idx = blockIdx.x * 256 + threadIdx.x;
    if (idx >= 3 * 64 * 192) return;
    int j = idx % 192;
    int n = (idx / 192) % 64;
    int L = idx / (192 * 64);
    const float* W = (L == 0) ? W1 : (L == 1) ? W2 : W3;
    float v = (j < 128) ? W[n * 192 + (j >> 1) * 3 + (j & 1)]
                        : W[n * 192 + (j - 128) * 3 + 2];
    P[idx] = f2bf(v);
}

__global__ __launch_bounds__(256, 6) void dijet_main(
    const float* __restrict__ x, const float* __restrict__ d,
    const float* __restrict__ b1, const float* __restrict__ b2,
    const float* __restrict__ b3, const unsigned short* __restrict__ Wp,
    float* __restrict__ out)
{
    // Ax: static x-part [row][j<128], XOR-swizzled, never rewritten. 12288 B.
    // Dd: double-buffered d-part [2][row][i<64], XOR-swizzled. 12288 B.
    // Epilogue overlays Ct (48*64 fp32 = 12288 B) onto Ax (dead after layer-3 MFMAs).
    __shared__ __align__(16) unsigned short Ax[ROWS * 128];
    __shared__ __align__(16) unsigned short Dd[2][ROWS * 64];
    float* Ct = (float*)Ax;

    const int t  = threadIdx.x;
    const int b0 = blockIdx.x * SPB;

    // ---- stage d (coalesced float2; residual kept in regs; scatter to Dd[0])
    float2 dres[6];
    {
        const float2* d2 = (const float2*)(d + (size_t)b0 * (ND * NPAIR));
        #pragma unroll
        for (int m = 0; m < 6; ++m) dres[m] = d2[m * 256 + t];
        #pragma unroll
        for (int m = 0; m < 6; ++m) {
            int idx = m * 256 + t;                // 0..1535 float2 elements
            int e   = idx * 2;
            int b   = e / 384;
            int rem = e - b * 384;
            int i   = rem / 6;                    // channel
            int s   = rem - i * 6;                // even slot
            int row = b * 6 + s;
            Dd[0][row * 64       + swzD(row, i >> 3) * 8     + (i & 7)] = f2bf(dres[m].x);
            Dd[0][(row + 1) * 64 + swzD(row + 1, i >> 3) * 8 + (i & 7)] = f2bf(dres[m].y);
        }
    }
    // ---- stage x (coalesced float4; convert + swizzled scatter to Ax)
    {
        const float4* x4 = (const float4*)(x + (size_t)b0 * (ND * 12));
        float4 v[6];
        #pragma unroll
        for (int m = 0; m < 6; ++m) v[m] = x4[m * 256 + t];
        unsigned* Ax32 = (unsigned*)Ax;
        #pragma unroll
        for (int m = 0; m < 6; ++m) {
            int idx = m * 256 + t;                // 0..1535 float4 elements
            int b   = idx / 192;                  // 192 float4 per sample
            int rem = idx - b * 192;
            int i   = rem / 3;                    // channel
            int c0  = (rem - i * 3) * 4;          // x-col base: 0,4,8
            int row0 = b * 6 + (c0 >> 1);         // slot = col/2
            int row1 = row0 + 1;
            int c    = i >> 2;                    // 16B chunk of j=2i
            Ax32[row0 * 64 + swzAx(row0, c) * 4 + (i & 3)] = f2bf2(v[m].x, v[m].y);
            Ax32[row1 * 64 + swzAx(row1, c) * 4 + (i & 3)] = f2bf2(v[m].z, v[m].w);
        }
    }
    __syncthreads();

    const int wave = t >> 6;
    const int lane = t & 63;
    const int l15  = lane & 15;
    const int quad = lane >> 4;
    const int nbase = wave * 16;                  // each wave: all 48 rows x its 16 cols

    int cur = 0;
    #pragma unroll
    for (int L = 0; L < 3; ++L) {
        const float* bL = (L == 0) ? b1 : (L == 1) ? b2 : b3;
        const unsigned short* WL = Wp + L * (64 * 192);

        // B fragments for this wave's 16 output cols (L2-resident packed weights)
        bf16x8 Bf[6];
        #pragma unroll
        for (int kk = 0; kk < 6; ++kk)
            Bf[kk] = *(const bf16x8*)(WL + (nbase + l15) * 192 + kk * 32 + quad * 8);
        float bias = bL[nbase + l15];

        floatx4 acc[3] = {};
        #pragma unroll
        for (int kk = 0; kk < 4; ++kk) {          // x-part K (conflict-free swizzled reads)
            #pragma unroll
            for (int mt = 0; mt < 3; ++mt) {
                int row = mt * 16 + l15;
                bf16x8 Af = *(const bf16x8*)(Ax + row * 128 + swzAx(row, kk * 4 + quad) * 8);
                acc[mt] = __builtin_amdgcn_mfma_f32_16x16x32_bf16(Af, Bf[kk], acc[mt], 0, 0, 0);
            }
        }
        #pragma unroll
        for (int kz = 0; kz < 2; ++kz) {          // d-part K
            #pragma unroll
            for (int mt = 0; mt < 3; ++mt) {
                int row = mt * 16 + l15;
                bf16x8 Af = *(const bf16x8*)(Dd[cur] + row * 64 + swzD(row, kz * 4 + quad) * 8);
                acc[mt] = __builtin_amdgcn_mfma_f32_16x16x32_bf16(Af, Bf[4 + kz], acc[mt], 0, 0, 0);
            }
        }

        const int o = nbase + l15;
        if (L < 2) {
            // write new d into the OTHER buffer: no WAR hazard -> single barrier per layer
            #pragma unroll
            for (int mt = 0; mt < 3; ++mt) {
                #pragma unroll
                for (int r = 0; r < 4; ++r) {
                    int row = mt * 16 + quad * 4 + r;   // C/D: col=lane&15, row=quad*4+reg
                    float v = acc[mt][r] + bias;
                    v = v > 0.f ? v : 0.f;
                    Dd[cur ^ 1][row * 64 + swzD(row, o >> 3) * 8 + (o & 7)] = f2bf(v);
                }
            }
            __syncthreads();   // new d visible; old buffer now dead
            cur ^= 1;
        } else {
            __syncthreads();   // all waves done reading Ax/Dd; safe to overlay Ct
            #pragma unroll
            for (int mt = 0; mt < 3; ++mt) {
                #pragma unroll
                for (int r = 0; r < 4; ++r) {
                    int row = mt * 16 + quad * 4 + r;
                    int bl  = row / 6;
                    int s   = row - bl * 6;
                    Ct[bl * (ND * NPAIR) + o * NPAIR + s] = acc[mt][r] + bias;
                }
            }
            __syncthreads();
            // coalesced float2 stores fused with register-resident residual
            float2* out2 = (float2*)(out + (size_t)b0 * (ND * NPAIR));
            const float2* Ct2 = (const float2*)Ct;
            #pragma unroll
            for (int m = 0; m < 6; ++m) {
                int idx = m * 256 + t;
                float2 c = Ct2[idx];
                float2 r;
                r.x = c.x + dres[m].x; r.x = r.x > 0.f ? r.x : 0.f;
                r.y = c.y + dres[m].y; r.y = r.y > 0.f ? r.y : 0.f;
                out2[idx] = r;
            }
        }
    }
}

extern "C" void kernel_launch(void* const* d_in, const int* in_sizes, int n_in,
                              void* d_out, int out_size, void* d_ws, size_t ws_size,
                              hipStream_t stream)
{
    const float* x  = (const float*)d_in[0];
    const float* dd = (const float*)d_in[1];
    const float* W1 = (const float*)d_in[2];
    const float* b1 = (const float*)d_in[3];
    const float* W2 = (const float*)d_in[4];
    const float* b2 = (const float*)d_in[5];
    const float* W3 = (const float*)d_in[6];
    const float* b3 = (const float*)d_in[7];
    float* out = (float*)d_out;
    unsigned short* Wp = (unsigned short*)d_ws;   // 3*64*192*2 = 73728 B

    int n = in_sizes[0] / (ND * 12);              // 65536

    repack_w<<<144, 256, 0, stream>>>(W1, W2, W3, Wp);
    dijet_main<<<n / SPB, 256, 0, stream>>>(x, dd, b1, b2, b3, Wp, out);
}